// Round 1
// baseline (119.859 us; speedup 1.0000x reference)
//
#include <hip/hip_runtime.h>
#include <stdint.h>

#define IN_DIM 1024
#define OUT_DIM 1024
#define NROWS 8192
#define KDIM (IN_DIM * 4)   // 4096, flattened (i,k)

#define BM 128
#define BN 128
#define BK 64

typedef __bf16 bf16x8 __attribute__((ext_vector_type(8)));
typedef float f32x4 __attribute__((ext_vector_type(4)));
typedef unsigned short us8 __attribute__((ext_vector_type(8)));
typedef unsigned int u32;

__device__ __forceinline__ unsigned short f2bf(float f) {
    u32 u = __builtin_bit_cast(u32, f);
    u32 r = (u + 0x7fffu + ((u >> 16) & 1u)) >> 16;   // RNE, finite inputs
    return (unsigned short)r;
}

// ---- prep: coeffs fp32 -> bf16 (B matrix, [OUT_DIM][KDIM] row-major) ----
__global__ void prep_coeffs(const float* __restrict__ c, unsigned short* __restrict__ B) {
    int t = blockIdx.x * blockDim.x + threadIdx.x;   // each handles 4 floats
    float4 v = reinterpret_cast<const float4*>(c)[t];
    ushort4 o;
    o.x = f2bf(v.x); o.y = f2bf(v.y); o.z = f2bf(v.z); o.w = f2bf(v.w);
    reinterpret_cast<ushort4*>(B)[t] = o;
}

// ---- prep: powers of x -> bf16 (A matrix, [NROWS][KDIM] row-major) ----
__global__ void prep_powers(const float* __restrict__ x, unsigned short* __restrict__ A) {
    int t = blockIdx.x * blockDim.x + threadIdx.x;   // each handles 4 x values -> 16 bf16
    float4 v = reinterpret_cast<const float4*>(x)[t];
    alignas(16) unsigned short o[16];
    float xs[4] = {v.x, v.y, v.z, v.w};
#pragma unroll
    for (int j = 0; j < 4; ++j) {
        float x1 = xs[j], x2 = x1 * x1, x3 = x2 * x1;
        o[j * 4 + 0] = 0x3f80u;      // bf16(1.0)
        o[j * 4 + 1] = f2bf(x1);
        o[j * 4 + 2] = f2bf(x2);
        o[j * 4 + 3] = f2bf(x3);
    }
    uint4* dst = reinterpret_cast<uint4*>(A + (size_t)t * 16);
    dst[0] = reinterpret_cast<uint4*>(o)[0];
    dst[1] = reinterpret_cast<uint4*>(o)[1];
}

// ---- main GEMM: C[M][N] = A[M][K] * B[N][K]^T + bias ----
__global__ __launch_bounds__(256) void taylor_gemm(
    const unsigned short* __restrict__ A,   // bf16 [NROWS][KDIM]
    const unsigned short* __restrict__ B,   // bf16 [OUT_DIM][KDIM]
    const float* __restrict__ bias,
    float* __restrict__ C) {
    __shared__ alignas(16) unsigned short sA[BM * BK];
    __shared__ alignas(16) unsigned short sB[BN * BK];

    const int tid = threadIdx.x;
    const int lane = tid & 63;
    const int wid = tid >> 6;
    const int wr = wid >> 1, wc = wid & 1;
    const int bx = blockIdx.x, by = blockIdx.y;

    // global_load_lds staging: each wave-issue moves 64 lanes * 16B = 1 KiB
    // (8 rows of a 128B-wide K-slice). dest = uniform base + lane*16.
    const char* Ab = (const char*)A;
    const char* Bb = (const char*)B;
    size_t aSrc[4], bSrc[4];
#pragma unroll
    for (int s = 0; s < 4; ++s) {
        int seg = wid * 4 + s;
        int row = seg * 8 + (lane >> 3);
        aSrc[s] = ((size_t)(by * BM + row) * KDIM) * 2 + (size_t)(lane & 7) * 16;
        bSrc[s] = ((size_t)(bx * BN + row) * KDIM) * 2 + (size_t)(lane & 7) * 16;
    }

    // fragment read bases (ushort index): row (lane&15), k-chunk (lane>>4)*8
    const int aBase = (wr * 64 + (lane & 15)) * BK + (lane >> 4) * 8;
    const int bBase = (wc * 64 + (lane & 15)) * BK + (lane >> 4) * 8;

    f32x4 acc[4][4] = {};

    for (int kt = 0; kt < KDIM / BK; ++kt) {
        size_t koff = (size_t)kt * (BK * 2);
#pragma unroll
        for (int s = 0; s < 4; ++s) {
            int seg = wid * 4 + s;
            __builtin_amdgcn_global_load_lds(
                (const __attribute__((address_space(1))) void*)(Ab + aSrc[s] + koff),
                (__attribute__((address_space(3))) void*)(&sA[seg * 512]), 16, 0, 0);
            __builtin_amdgcn_global_load_lds(
                (const __attribute__((address_space(1))) void*)(Bb + bSrc[s] + koff),
                (__attribute__((address_space(3))) void*)(&sB[seg * 512]), 16, 0, 0);
        }
        __syncthreads();
#pragma unroll
        for (int ks = 0; ks < 2; ++ks) {
            bf16x8 af[4], bfr[4];
#pragma unroll
            for (int m = 0; m < 4; ++m)
                af[m] = __builtin_bit_cast(bf16x8,
                    *reinterpret_cast<const us8*>(&sA[aBase + m * 16 * BK + ks * 32]));
#pragma unroll
            for (int n = 0; n < 4; ++n)
                bfr[n] = __builtin_bit_cast(bf16x8,
                    *reinterpret_cast<const us8*>(&sB[bBase + n * 16 * BK + ks * 32]));
#pragma unroll
            for (int m = 0; m < 4; ++m)
#pragma unroll
                for (int n = 0; n < 4; ++n)
                    acc[m][n] = __builtin_amdgcn_mfma_f32_16x16x32_bf16(
                        af[m], bfr[n], acc[m][n], 0, 0, 0);
        }
        __syncthreads();
    }

    // epilogue: C/D layout col = lane&15, row = (lane>>4)*4 + r
    const int colBase = bx * BN + wc * 64 + (lane & 15);
    const int rowBase = by * BM + wr * 64 + (lane >> 4) * 4;
#pragma unroll
    for (int n = 0; n < 4; ++n) {
        int col = colBase + n * 16;
        float bv = bias[col];
#pragma unroll
        for (int m = 0; m < 4; ++m) {
            int row = rowBase + m * 16;
#pragma unroll
            for (int r = 0; r < 4; ++r)
                C[(size_t)(row + r) * OUT_DIM + col] = acc[m][n][r] + bv;
        }
    }
}

// ---- fallback (ws too small): fp32 LDS-staged, correct but slow ----
__global__ void taylor_naive(const float* __restrict__ x, const float* __restrict__ coeffs,
                             const float* __restrict__ bias, float* __restrict__ out) {
    int n = blockIdx.x;
    __shared__ float P[IN_DIM * 4];
    for (int i = threadIdx.x; i < IN_DIM; i += blockDim.x) {
        float xv = x[(size_t)n * IN_DIM + i];
        P[i * 4 + 0] = 1.f;
        P[i * 4 + 1] = xv;
        P[i * 4 + 2] = xv * xv;
        P[i * 4 + 3] = xv * xv * xv;
    }
    __syncthreads();
    for (int o = threadIdx.x; o < OUT_DIM; o += blockDim.x) {
        float s = bias[o];
        const float* c = coeffs + (size_t)o * KDIM;
        for (int i = 0; i < IN_DIM; ++i) {
            float4 cv = *reinterpret_cast<const float4*>(c + i * 4);
            s += cv.x * P[i * 4 + 0] + cv.y * P[i * 4 + 1] +
                 cv.z * P[i * 4 + 2] + cv.w * P[i * 4 + 3];
        }
        out[(size_t)n * OUT_DIM + o] = s;
    }
}

extern "C" void kernel_launch(void* const* d_in, const int* in_sizes, int n_in,
                              void* d_out, int out_size, void* d_ws, size_t ws_size,
                              hipStream_t stream) {
    const float* x = (const float*)d_in[0];
    const float* coeffs = (const float*)d_in[1];
    const float* bias = (const float*)d_in[2];
    float* out = (float*)d_out;

    const size_t needA = (size_t)NROWS * KDIM * 2;    // 64 MiB
    const size_t needB = (size_t)OUT_DIM * KDIM * 2;  // 8 MiB

    if (ws_size >= needA + needB) {
        unsigned short* A = (unsigned short*)d_ws;
        unsigned short* B = (unsigned short*)((char*)d_ws + needA);
        prep_coeffs<<<(OUT_DIM * KDIM / 4) / 256, 256, 0, stream>>>(coeffs, B);
        prep_powers<<<(NROWS * IN_DIM / 4) / 256, 256, 0, stream>>>(x, A);
        dim3 grid(OUT_DIM / BN, NROWS / BM);
        taylor_gemm<<<grid, 256, 0, stream>>>(A, B, bias, out);
    } else {
        taylor_naive<<<NROWS, 256, 0, stream>>>(x, coeffs, bias, out);
    }
}

// Round 2
// 110.908 us; speedup vs baseline: 1.0807x; 1.0807x over previous
//
#include <hip/hip_runtime.h>
#include <stdint.h>

#define IN_DIM 1024
#define OUT_DIM 1024
#define NROWS 8192
#define KD 3072            // k-major: K = (p-1)*1024 + i, p = 1..3 (k=0 folded into bias)

#define BM 128
#define BN 128
#define BK 64
#define NT (KD / BK)       // 48 K-steps

typedef __bf16 bf16x8 __attribute__((ext_vector_type(8)));
typedef float f32x4 __attribute__((ext_vector_type(4)));
typedef unsigned short us8 __attribute__((ext_vector_type(8)));
typedef unsigned int u32;

#define AS1 __attribute__((address_space(1)))
#define AS3 __attribute__((address_space(3)))

__device__ __forceinline__ unsigned short f2bf(float f) {
    u32 u = __builtin_bit_cast(u32, f);
    u32 r = (u + 0x7fffu + ((u >> 16) & 1u)) >> 16;   // RNE, finite inputs
    return (unsigned short)r;
}

// ---- prep: coeffs fp32 -> bf16 B[OUT_DIM][KD] (k-major), c0 folded into bias2 ----
__global__ __launch_bounds__(256) void prep_coeffs(const float* __restrict__ c,
                                                   const float* __restrict__ bias,
                                                   unsigned short* __restrict__ B,
                                                   float* __restrict__ bias2) {
    const int o = blockIdx.x;
    const float4* row = reinterpret_cast<const float4*>(c + (size_t)o * (IN_DIM * 4));
    unsigned short* Bo = B + (size_t)o * KD;
    float s = 0.f;
    for (int i = threadIdx.x; i < IN_DIM; i += 256) {
        float4 v = row[i];            // {c0, c1, c2, c3} for (o, i)
        s += v.x;
        Bo[i]            = f2bf(v.y);
        Bo[1024 + i]     = f2bf(v.z);
        Bo[2048 + i]     = f2bf(v.w);
    }
#pragma unroll
    for (int off = 32; off; off >>= 1) s += __shfl_down(s, off);
    __shared__ float red[4];
    if ((threadIdx.x & 63) == 0) red[threadIdx.x >> 6] = s;
    __syncthreads();
    if (threadIdx.x == 0) bias2[o] = bias[o] + red[0] + red[1] + red[2] + red[3];
}

// ---- prep: powers of x -> bf16 A[NROWS][KD] (k-major) ----
__global__ __launch_bounds__(256) void prep_powers(const float* __restrict__ x,
                                                   unsigned short* __restrict__ A) {
    int t = blockIdx.x * blockDim.x + threadIdx.x;    // each handles 4 x values
    int n = t >> 8;                                   // 256 float4 per row
    int i4 = (t & 255) * 4;
    float4 v = reinterpret_cast<const float4*>(x)[t];
    unsigned short* An = A + (size_t)n * KD + i4;
    ushort4 p1, p2, p3;
    float xs[4] = {v.x, v.y, v.z, v.w};
    unsigned short b1[4], b2[4], b3[4];
#pragma unroll
    for (int j = 0; j < 4; ++j) {
        float x1 = xs[j], x2 = x1 * x1, x3 = x2 * x1;
        b1[j] = f2bf(x1); b2[j] = f2bf(x2); b3[j] = f2bf(x3);
    }
    p1 = {b1[0], b1[1], b1[2], b1[3]};
    p2 = {b2[0], b2[1], b2[2], b2[3]};
    p3 = {b3[0], b3[1], b3[2], b3[3]};
    *reinterpret_cast<ushort4*>(An)        = p1;
    *reinterpret_cast<ushort4*>(An + 1024) = p2;
    *reinterpret_cast<ushort4*>(An + 2048) = p3;
}

// ---- main GEMM: C[M][N] = A[M][KD] * B[N][KD]^T + bias2 ----
// grid = (NROWS/BM, OUT_DIM/BN): blockIdx.x = row-panel (by) so consecutive
// dispatches read DISTINCT A-panels (dedup across XCD L2s) and share the
// small B-panel (768 KB, L2-resident).
__global__ __launch_bounds__(256) void taylor_gemm(
    const unsigned short* __restrict__ A,   // bf16 [NROWS][KD]
    const unsigned short* __restrict__ B,   // bf16 [OUT_DIM][KD]
    const float* __restrict__ bias2,
    float* __restrict__ C) {
    __shared__ alignas(16) unsigned short sA[2][BM * BK];
    __shared__ alignas(16) unsigned short sB[2][BN * BK];

    const int tid = threadIdx.x;
    const int lane = tid & 63;
    const int wid = tid >> 6;
    const int wr = wid >> 1, wc = wid & 1;
    const int by = blockIdx.x, bx = blockIdx.y;

    const char* Ab = (const char*)A;
    const char* Bb = (const char*)B;
    size_t aSrc[4], bSrc[4];
#pragma unroll
    for (int s = 0; s < 4; ++s) {
        int seg = wid * 4 + s;
        int row = seg * 8 + (lane >> 3);
        aSrc[s] = ((size_t)(by * BM + row) * KD) * 2 + (size_t)(lane & 7) * 16;
        bSrc[s] = ((size_t)(bx * BN + row) * KD) * 2 + (size_t)(lane & 7) * 16;
    }

    // fragment read bases (ushort index): row (lane&15), k-chunk (lane>>4)*8
    const int aBase = (wr * 64 + (lane & 15)) * BK + (lane >> 4) * 8;
    const int bBase = (wc * 64 + (lane & 15)) * BK + (lane >> 4) * 8;

    f32x4 acc[4][4] = {};

    auto stage = [&](int buf, int kt) {
        size_t koff = (size_t)kt * (BK * 2);
#pragma unroll
        for (int s = 0; s < 4; ++s) {
            int seg = wid * 4 + s;
            __builtin_amdgcn_global_load_lds(
                (const AS1 void*)(Ab + aSrc[s] + koff),
                (AS3 void*)(&sA[buf][seg * 512]), 16, 0, 0);
            __builtin_amdgcn_global_load_lds(
                (const AS1 void*)(Bb + bSrc[s] + koff),
                (AS3 void*)(&sB[buf][seg * 512]), 16, 0, 0);
        }
    };

    auto compute = [&](int buf) {
#pragma unroll
        for (int ks = 0; ks < 2; ++ks) {
            bf16x8 af[4], bfr[4];
#pragma unroll
            for (int m = 0; m < 4; ++m)
                af[m] = __builtin_bit_cast(bf16x8,
                    *reinterpret_cast<const us8*>(&sA[buf][aBase + m * 16 * BK + ks * 32]));
#pragma unroll
            for (int n = 0; n < 4; ++n)
                bfr[n] = __builtin_bit_cast(bf16x8,
                    *reinterpret_cast<const us8*>(&sB[buf][bBase + n * 16 * BK + ks * 32]));
#pragma unroll
            for (int m = 0; m < 4; ++m)
#pragma unroll
                for (int n = 0; n < 4; ++n)
                    acc[m][n] = __builtin_amdgcn_mfma_f32_16x16x32_bf16(
                        af[m], bfr[n], acc[m][n], 0, 0, 0);
        }
    };

    // stage-ahead double-buffered pipeline: one barrier per K-step,
    // next tile's loads in flight under current tile's MFMA.
    stage(0, 0);
    __syncthreads();                 // drains vmcnt(0)
    int cur = 0;
    for (int kt = 0; kt < NT - 1; ++kt) {
        stage(cur ^ 1, kt + 1);      // issue next-tile loads first
        compute(cur);                // MFMA hides the load latency
        __syncthreads();             // vmcnt(0)+lgkmcnt(0) drain, buffer handoff
        cur ^= 1;
    }
    compute(cur);

    // epilogue: C/D layout col = lane&15, row = (lane>>4)*4 + r
    const int colBase = bx * BN + wc * 64 + (lane & 15);
    const int rowBase = by * BM + wr * 64 + (lane >> 4) * 4;
#pragma unroll
    for (int n = 0; n < 4; ++n) {
        int col = colBase + n * 16;
        float bv = bias2[col];
#pragma unroll
        for (int m = 0; m < 4; ++m) {
            int row = rowBase + m * 16;
#pragma unroll
            for (int r = 0; r < 4; ++r)
                C[(size_t)(row + r) * OUT_DIM + col] = acc[m][n][r] + bv;
        }
    }
}

// ---- fallback (ws too small): fp32 LDS-staged, correct but slow ----
__global__ void taylor_naive(const float* __restrict__ x, const float* __restrict__ coeffs,
                             const float* __restrict__ bias, float* __restrict__ out) {
    int n = blockIdx.x;
    __shared__ float P[IN_DIM * 4];
    for (int i = threadIdx.x; i < IN_DIM; i += blockDim.x) {
        float xv = x[(size_t)n * IN_DIM + i];
        P[i * 4 + 0] = 1.f;
        P[i * 4 + 1] = xv;
        P[i * 4 + 2] = xv * xv;
        P[i * 4 + 3] = xv * xv * xv;
    }
    __syncthreads();
    for (int o = threadIdx.x; o < OUT_DIM; o += blockDim.x) {
        float s = bias[o];
        const float* c = coeffs + (size_t)o * (IN_DIM * 4);
        for (int i = 0; i < IN_DIM; ++i) {
            float4 cv = *reinterpret_cast<const float4*>(c + i * 4);
            s += cv.x * P[i * 4 + 0] + cv.y * P[i * 4 + 1] +
                 cv.z * P[i * 4 + 2] + cv.w * P[i * 4 + 3];
        }
        out[(size_t)n * OUT_DIM + o] = s;
    }
}

extern "C" void kernel_launch(void* const* d_in, const int* in_sizes, int n_in,
                              void* d_out, int out_size, void* d_ws, size_t ws_size,
                              hipStream_t stream) {
    const float* x = (const float*)d_in[0];
    const float* coeffs = (const float*)d_in[1];
    const float* bias = (const float*)d_in[2];
    float* out = (float*)d_out;

    const size_t needA = (size_t)NROWS * KD * 2;     // 48 MiB
    const size_t needB = (size_t)OUT_DIM * KD * 2;   // 6 MiB
    const size_t needBias = OUT_DIM * sizeof(float); // 4 KiB

    if (ws_size >= needA + needB + needBias) {
        unsigned short* A = (unsigned short*)d_ws;
        unsigned short* B = (unsigned short*)((char*)d_ws + needA);
        float* bias2 = (float*)((char*)d_ws + needA + needB);
        prep_coeffs<<<OUT_DIM, 256, 0, stream>>>(coeffs, bias, B, bias2);
        prep_powers<<<(NROWS * IN_DIM / 4) / 256, 256, 0, stream>>>(x, A);
        dim3 grid(NROWS / BM, OUT_DIM / BN);   // (64, 8): row-panel fastest
        taylor_gemm<<<grid, 256, 0, stream>>>(A, B, bias2, out);
    } else {
        taylor_naive<<<NROWS, 256, 0, stream>>>(x, coeffs, bias, out);
    }
}

// Round 3
// 100.963 us; speedup vs baseline: 1.1872x; 1.0985x over previous
//
#include <hip/hip_runtime.h>
#include <stdint.h>

#define IN_DIM 1024
#define OUT_DIM 1024
#define NROWS 8192
#define KD 3072            // k-major: K = (p-1)*1024 + i, p = 1..3 (k=0 folded into bias)

#define BM 256
#define BN 128
#define BK 64
#define NT (KD / BK)       // 48 K-tiles

typedef __bf16 bf16x8 __attribute__((ext_vector_type(8)));
typedef float f32x4 __attribute__((ext_vector_type(4)));
typedef unsigned short us8 __attribute__((ext_vector_type(8)));
typedef unsigned int u32;

#define AS1 __attribute__((address_space(1)))
#define AS3 __attribute__((address_space(3)))

__device__ __forceinline__ unsigned short f2bf(float f) {
    u32 u = __builtin_bit_cast(u32, f);
    u32 r = (u + 0x7fffu + ((u >> 16) & 1u)) >> 16;   // RNE, finite inputs
    return (unsigned short)r;
}

// ---- prep: coeffs fp32 -> bf16 B[OUT_DIM][KD] (k-major), c0 folded into bias2 ----
__global__ __launch_bounds__(256) void prep_coeffs(const float* __restrict__ c,
                                                   const float* __restrict__ bias,
                                                   unsigned short* __restrict__ B,
                                                   float* __restrict__ bias2) {
    const int o = blockIdx.x;
    const float4* row = reinterpret_cast<const float4*>(c + (size_t)o * (IN_DIM * 4));
    unsigned short* Bo = B + (size_t)o * KD;
    float s = 0.f;
    for (int i = threadIdx.x; i < IN_DIM; i += 256) {
        float4 v = row[i];            // {c0, c1, c2, c3} for (o, i)
        s += v.x;
        Bo[i]        = f2bf(v.y);
        Bo[1024 + i] = f2bf(v.z);
        Bo[2048 + i] = f2bf(v.w);
    }
#pragma unroll
    for (int off = 32; off; off >>= 1) s += __shfl_down(s, off);
    __shared__ float red[4];
    if ((threadIdx.x & 63) == 0) red[threadIdx.x >> 6] = s;
    __syncthreads();
    if (threadIdx.x == 0) bias2[o] = bias[o] + red[0] + red[1] + red[2] + red[3];
}

// ---- prep: powers of x -> bf16 A[NROWS][KD] (k-major) ----
__global__ __launch_bounds__(256) void prep_powers(const float* __restrict__ x,
                                                   unsigned short* __restrict__ A) {
    int t = blockIdx.x * blockDim.x + threadIdx.x;    // each handles 4 x values
    int n = t >> 8;                                   // 256 float4 per row
    int i4 = (t & 255) * 4;
    float4 v = reinterpret_cast<const float4*>(x)[t];
    unsigned short* An = A + (size_t)n * KD + i4;
    float xs[4] = {v.x, v.y, v.z, v.w};
    unsigned short b1[4], b2[4], b3[4];
#pragma unroll
    for (int j = 0; j < 4; ++j) {
        float x1 = xs[j], x2 = x1 * x1, x3 = x2 * x1;
        b1[j] = f2bf(x1); b2[j] = f2bf(x2); b3[j] = f2bf(x3);
    }
    ushort4 p1 = {b1[0], b1[1], b1[2], b1[3]};
    ushort4 p2 = {b2[0], b2[1], b2[2], b2[3]};
    ushort4 p3 = {b3[0], b3[1], b3[2], b3[3]};
    *reinterpret_cast<ushort4*>(An)        = p1;
    *reinterpret_cast<ushort4*>(An + 1024) = p2;
    *reinterpret_cast<ushort4*>(An + 2048) = p3;
}

// ---- main GEMM: C = A[M][KD] * B[N][KD]^T + bias2 ----
// 512 thr / 8 waves (2M x 4N); BM=256 BN=128 BK=64; triple-buffered LDS,
// stage-2-ahead with counted vmcnt (T3/T4), raw s_barrier (no vmcnt drain),
// setprio around MFMA clusters (T5). 1 block/CU (144 KiB LDS), grid 256.
__global__ __launch_bounds__(512, 1) void taylor_gemm(
    const unsigned short* __restrict__ A,   // bf16 [NROWS][KD]
    const unsigned short* __restrict__ B,   // bf16 [OUT_DIM][KD]
    const float* __restrict__ bias2,
    float* __restrict__ C) {
    __shared__ alignas(16) unsigned short sA[3][BM * BK];  // 3 x 32 KiB
    __shared__ alignas(16) unsigned short sB[3][BN * BK];  // 3 x 16 KiB

    const int tid = threadIdx.x;
    const int lane = tid & 63;
    const int wid = tid >> 6;       // 0..7
    const int wr = wid >> 2;        // 0..1  (M half)
    const int wc = wid & 3;         // 0..3  (N quarter)
    const int gx = blockIdx.x, gy = blockIdx.y;

    // ---- staging: 6 global_load_lds units/wave/tile (A:4, B:2) ----
    // unit u: wave-uniform LDS dest, per-lane global src; lane l lands at
    // dest_base + l*16 = row (lane>>3), k-bytes (lane&7)*16 within an 8-row slab.
    const char* Ab = (const char*)A;
    const char* Bb = (const char*)B;
    size_t aSrc[4], bSrc[2];
    int aDst[4], bDst[2];
#pragma unroll
    for (int u = 0; u < 4; ++u) {
        int row = gx * BM + u * 64 + wid * 8 + (lane >> 3);
        aSrc[u] = ((size_t)row * KD + (size_t)(lane & 7) * 8) * 2;
        aDst[u] = (u * 64 + wid * 8) * BK;
    }
#pragma unroll
    for (int u = 0; u < 2; ++u) {
        int row = gy * BN + u * 64 + wid * 8 + (lane >> 3);
        bSrc[u] = ((size_t)row * KD + (size_t)(lane & 7) * 8) * 2;
        bDst[u] = (u * 64 + wid * 8) * BK;
    }

    auto stage_unit = [&](int b, int kt, int u) {
        size_t koff = (size_t)kt * (BK * 2);
        if (u < 4)
            __builtin_amdgcn_global_load_lds(
                (const AS1 void*)(Ab + aSrc[u] + koff),
                (AS3 void*)(&sA[b][aDst[u]]), 16, 0, 0);
        else
            __builtin_amdgcn_global_load_lds(
                (const AS1 void*)(Bb + bSrc[u - 4] + koff),
                (AS3 void*)(&sB[b][bDst[u - 4]]), 16, 0, 0);
    };

    // fragment read bases (ushort index): row (lane&15), k-chunk (lane>>4)*8
    const int aBase = (wr * 128 + (lane & 15)) * BK + (lane >> 4) * 8;
    const int bBase = (wc * 32 + (lane & 15)) * BK + (lane >> 4) * 8;

    f32x4 acc[8][2] = {};

    // prologue: tiles 0,1 -> bufs 0,1 (12 units outstanding per wave)
#pragma unroll
    for (int u = 0; u < 6; ++u) stage_unit(0, 0, u);
#pragma unroll
    for (int u = 0; u < 6; ++u) stage_unit(1, 1, u);

    for (int kt = 0; kt < NT; ++kt) {
        const int cb = kt % 3;
        const int nb = (kt + 2) % 3;
        // wait: tile kt landed (newest 6 outstanding = tile kt+1)
        if (kt < NT - 1) asm volatile("s_waitcnt vmcnt(6)" ::: "memory");
        else             asm volatile("s_waitcnt vmcnt(0)" ::: "memory");
        __builtin_amdgcn_s_barrier();        // all waves' tile-kt units landed
        __builtin_amdgcn_sched_barrier(0);   // pin: no LDS reads above barrier

        const unsigned short* sAc = &sA[cb][0];
        const unsigned short* sBc = &sB[cb][0];
        const bool doStage = (kt < NT - 2);

        // B fragments for the whole tile (n x ks = 4 reads)
        bf16x8 bfr[2][2];
#pragma unroll
        for (int n = 0; n < 2; ++n)
#pragma unroll
            for (int ks = 0; ks < 2; ++ks)
                bfr[n][ks] = __builtin_bit_cast(bf16x8,
                    *reinterpret_cast<const us8*>(&sBc[bBase + n * 16 * BK + ks * 32]));

#pragma unroll
        for (int ph = 0; ph < 4; ++ph) {
            bf16x8 af[2][2];
#pragma unroll
            for (int mi = 0; mi < 2; ++mi)
#pragma unroll
                for (int ks = 0; ks < 2; ++ks)
                    af[mi][ks] = __builtin_bit_cast(bf16x8,
                        *reinterpret_cast<const us8*>(
                            &sAc[aBase + (ph * 2 + mi) * 16 * BK + ks * 32]));
            // interleave next-next tile staging: ph0:{0,4} ph1:{1,5} ph2:{2} ph3:{3}
            if (doStage) {
                stage_unit(nb, kt + 2, ph);
                if (ph < 2) stage_unit(nb, kt + 2, 4 + ph);
            }
            asm volatile("s_waitcnt lgkmcnt(0)" ::: "memory");
            __builtin_amdgcn_sched_barrier(0);   // rule #18: keep MFMA below wait
            __builtin_amdgcn_s_setprio(1);
#pragma unroll
            for (int mi = 0; mi < 2; ++mi)
#pragma unroll
                for (int n = 0; n < 2; ++n)
#pragma unroll
                    for (int ks = 0; ks < 2; ++ks)
                        acc[ph * 2 + mi][n] = __builtin_amdgcn_mfma_f32_16x16x32_bf16(
                            af[mi][ks], bfr[n][ks], acc[ph * 2 + mi][n], 0, 0, 0);
            __builtin_amdgcn_s_setprio(0);
        }
    }

    // epilogue: C/D layout col = lane&15, row = (lane>>4)*4 + r
    const int colBase = gy * BN + wc * 32 + (lane & 15);
    const int rowBase = gx * BM + wr * 128 + (lane >> 4) * 4;
#pragma unroll
    for (int n = 0; n < 2; ++n) {
        int col = colBase + n * 16;
        float bv = bias2[col];
#pragma unroll
        for (int m = 0; m < 8; ++m) {
            int row = rowBase + m * 16;
#pragma unroll
            for (int r = 0; r < 4; ++r)
                C[(size_t)(row + r) * OUT_DIM + col] = acc[m][n][r] + bv;
        }
    }
}

// ---- fallback (ws too small): fp32 LDS-staged, correct but slow ----
__global__ void taylor_naive(const float* __restrict__ x, const float* __restrict__ coeffs,
                             const float* __restrict__ bias, float* __restrict__ out) {
    int n = blockIdx.x;
    __shared__ float P[IN_DIM * 4];
    for (int i = threadIdx.x; i < IN_DIM; i += blockDim.x) {
        float xv = x[(size_t)n * IN_DIM + i];
        P[i * 4 + 0] = 1.f;
        P[i * 4 + 1] = xv;
        P[i * 4 + 2] = xv * xv;
        P[i * 4 + 3] = xv * xv * xv;
    }
    __syncthreads();
    for (int o = threadIdx.x; o < OUT_DIM; o += blockDim.x) {
        float s = bias[o];
        const float* c = coeffs + (size_t)o * (IN_DIM * 4);
        for (int i = 0; i < IN_DIM; ++i) {
            float4 cv = *reinterpret_cast<const float4*>(c + i * 4);
            s += cv.x * P[i * 4 + 0] + cv.y * P[i * 4 + 1] +
                 cv.z * P[i * 4 + 2] + cv.w * P[i * 4 + 3];
        }
        out[(size_t)n * OUT_DIM + o] = s;
    }
}

extern "C" void kernel_launch(void* const* d_in, const int* in_sizes, int n_in,
                              void* d_out, int out_size, void* d_ws, size_t ws_size,
                              hipStream_t stream) {
    const float* x = (const float*)d_in[0];
    const float* coeffs = (const float*)d_in[1];
    const float* bias = (const float*)d_in[2];
    float* out = (float*)d_out;

    const size_t needA = (size_t)NROWS * KD * 2;     // 48 MiB
    const size_t needB = (size_t)OUT_DIM * KD * 2;   // 6 MiB
    const size_t needBias = OUT_DIM * sizeof(float); // 4 KiB

    if (ws_size >= needA + needB + needBias) {
        unsigned short* A = (unsigned short*)d_ws;
        unsigned short* B = (unsigned short*)((char*)d_ws + needA);
        float* bias2 = (float*)((char*)d_ws + needA + needB);
        prep_coeffs<<<OUT_DIM, 256, 0, stream>>>(coeffs, bias, B, bias2);
        prep_powers<<<(NROWS * IN_DIM / 4) / 256, 256, 0, stream>>>(x, A);
        dim3 grid(NROWS / BM, OUT_DIM / BN);   // (32, 8) = 256 blocks, 1/CU
        taylor_gemm<<<grid, 512, 0, stream>>>(A, B, bias2, out);
    } else {
        taylor_naive<<<NROWS, 256, 0, stream>>>(x, coeffs, bias, out);
    }
}

// Round 4
// 90.061 us; speedup vs baseline: 1.3309x; 1.1210x over previous
//
#include <hip/hip_runtime.h>
#include <stdint.h>

#define IN_DIM 1024
#define OUT_DIM 1024
#define NROWS 8192
#define KD 3072            // k-major: K = (p-1)*1024 + i, p = 1..3 (k=0 folded into bias)

#define BM 256
#define BN 128
#define BK 64
#define NT (KD / BK)       // 48 K-tiles

typedef __bf16 bf16x8 __attribute__((ext_vector_type(8)));
typedef float f32x4 __attribute__((ext_vector_type(4)));
typedef unsigned short us8 __attribute__((ext_vector_type(8)));
typedef unsigned int u32;

#define AS1 __attribute__((address_space(1)))
#define AS3 __attribute__((address_space(3)))

__device__ __forceinline__ unsigned short f2bf(float f) {
    u32 u = __builtin_bit_cast(u32, f);
    u32 r = (u + 0x7fffu + ((u >> 16) & 1u)) >> 16;   // RNE, finite inputs
    return (unsigned short)r;
}

// ---- prep: coeffs fp32 -> bf16 B[OUT_DIM][KD] (k-major), c0 folded into bias2 ----
__global__ __launch_bounds__(256) void prep_coeffs(const float* __restrict__ c,
                                                   const float* __restrict__ bias,
                                                   unsigned short* __restrict__ B,
                                                   float* __restrict__ bias2) {
    const int o = blockIdx.x;
    const float4* row = reinterpret_cast<const float4*>(c + (size_t)o * (IN_DIM * 4));
    unsigned short* Bo = B + (size_t)o * KD;
    float s = 0.f;
    for (int i = threadIdx.x; i < IN_DIM; i += 256) {
        float4 v = row[i];            // {c0, c1, c2, c3} for (o, i)
        s += v.x;
        Bo[i]        = f2bf(v.y);
        Bo[1024 + i] = f2bf(v.z);
        Bo[2048 + i] = f2bf(v.w);
    }
#pragma unroll
    for (int off = 32; off; off >>= 1) s += __shfl_down(s, off);
    __shared__ float red[4];
    if ((threadIdx.x & 63) == 0) red[threadIdx.x >> 6] = s;
    __syncthreads();
    if (threadIdx.x == 0) bias2[o] = bias[o] + red[0] + red[1] + red[2] + red[3];
}

// ---- prep: powers of x -> bf16 A[NROWS][KD] (k-major) ----
__global__ __launch_bounds__(256) void prep_powers(const float* __restrict__ x,
                                                   unsigned short* __restrict__ A) {
    int t = blockIdx.x * blockDim.x + threadIdx.x;    // each handles 4 x values
    int n = t >> 8;                                   // 256 float4 per row
    int i4 = (t & 255) * 4;
    float4 v = reinterpret_cast<const float4*>(x)[t];
    unsigned short* An = A + (size_t)n * KD + i4;
    float xs[4] = {v.x, v.y, v.z, v.w};
    unsigned short b1[4], b2[4], b3[4];
#pragma unroll
    for (int j = 0; j < 4; ++j) {
        float x1 = xs[j], x2 = x1 * x1, x3 = x2 * x1;
        b1[j] = f2bf(x1); b2[j] = f2bf(x2); b3[j] = f2bf(x3);
    }
    ushort4 p1 = {b1[0], b1[1], b1[2], b1[3]};
    ushort4 p2 = {b2[0], b2[1], b2[2], b2[3]};
    ushort4 p3 = {b3[0], b3[1], b3[2], b3[3]};
    *reinterpret_cast<ushort4*>(An)        = p1;
    *reinterpret_cast<ushort4*>(An + 1024) = p2;
    *reinterpret_cast<ushort4*>(An + 2048) = p3;
}

// ---- main GEMM: C = A[M][KD] * B[N][KD]^T + bias2 ----
// 512 thr / 8 waves (4M x 2N, wave tile 64x64); BM=256 BN=128 BK=64.
// Triple-buffered LDS, stage-2-ahead counted vmcnt (T3/T4), setprio (T5),
// T2 XOR-swizzle: linear global_load_lds dest + inverse-swizzled global
// source + swizzled ds_read (rule #21). 1 block/CU, grid 256.
__global__ __launch_bounds__(512, 1) void taylor_gemm(
    const unsigned short* __restrict__ A,   // bf16 [NROWS][KD]
    const unsigned short* __restrict__ B,   // bf16 [OUT_DIM][KD]
    const float* __restrict__ bias2,
    float* __restrict__ C) {
    __shared__ alignas(16) unsigned short sA[3][BM * BK];  // 3 x 32 KiB
    __shared__ alignas(16) unsigned short sB[3][BN * BK];  // 3 x 16 KiB

    const int tid = threadIdx.x;
    const int lane = tid & 63;
    const int wid = tid >> 6;       // 0..7
    const int wr = wid >> 1;        // 0..3  (M quarter: 64 rows)
    const int wc = wid & 1;         // 0..1  (N half: 64 cols)
    const int gx = blockIdx.x, gy = blockIdx.y;

    // ---- staging: 6 global_load_lds units/wave/tile (A:4, B:2) ----
    // LDS dest is linear (base + lane*16). Source col-slot is XOR-permuted:
    // lane l (row r=l>>3, LDS slot t=l&7) loads global slot t^r, so that a
    // swizzled read addr r*128 + (s^(r&7))*16 yields global slot s.
    const char* Ab = (const char*)A;
    const char* Bb = (const char*)B;
    const int cs = ((lane & 7) ^ (lane >> 3)) * 8;   // swizzled source col (ushort)
    size_t aSrc[4], bSrc[2];
    int aDst[4], bDst[2];
#pragma unroll
    for (int u = 0; u < 4; ++u) {
        int row = gx * BM + u * 64 + wid * 8 + (lane >> 3);
        aSrc[u] = ((size_t)row * KD + cs) * 2;
        aDst[u] = (u * 64 + wid * 8) * BK;
    }
#pragma unroll
    for (int u = 0; u < 2; ++u) {
        int row = gy * BN + u * 64 + wid * 8 + (lane >> 3);
        bSrc[u] = ((size_t)row * KD + cs) * 2;
        bDst[u] = (u * 64 + wid * 8) * BK;
    }

    auto stage_unit = [&](int b, int kt, int u) {
        size_t koff = (size_t)kt * (BK * 2);
        if (u < 4)
            __builtin_amdgcn_global_load_lds(
                (const AS1 void*)(Ab + aSrc[u] + koff),
                (AS3 void*)(&sA[b][aDst[u]]), 16, 0, 0);
        else
            __builtin_amdgcn_global_load_lds(
                (const AS1 void*)(Bb + bSrc[u - 4] + koff),
                (AS3 void*)(&sB[b][bDst[u - 4]]), 16, 0, 0);
    };

    // swizzled fragment read bases (ushort index), per ks:
    // row r = waveBase + frag*16 + (lane&15)  (r&7 == lane&7)
    // slot s = ks*4 + (lane>>4);  addr = r*64 + (s ^ (lane&7))*8
    int aSw[2], bSw[2];
#pragma unroll
    for (int ks = 0; ks < 2; ++ks) {
        int sw = ((ks * 4 + (lane >> 4)) ^ (lane & 7)) * 8;
        aSw[ks] = (wr * 64 + (lane & 15)) * BK + sw;
        bSw[ks] = (wc * 64 + (lane & 15)) * BK + sw;
    }

    f32x4 acc[4][4] = {};

    // prologue: tiles 0,1 -> bufs 0,1 (12 units outstanding per wave)
#pragma unroll
    for (int u = 0; u < 6; ++u) stage_unit(0, 0, u);
#pragma unroll
    for (int u = 0; u < 6; ++u) stage_unit(1, 1, u);

    for (int kt = 0; kt < NT; ++kt) {
        const int cb = kt % 3;
        const int nb = (kt + 2) % 3;
        // wait: tile kt landed (newest 6 outstanding = tile kt+1)
        if (kt < NT - 1) asm volatile("s_waitcnt vmcnt(6)" ::: "memory");
        else             asm volatile("s_waitcnt vmcnt(0)" ::: "memory");
        __builtin_amdgcn_s_barrier();        // all waves' tile-kt units landed
        __builtin_amdgcn_sched_barrier(0);   // pin: no LDS reads above barrier

        const unsigned short* sAc = &sA[cb][0];
        const unsigned short* sBc = &sB[cb][0];
        const bool doStage = (kt < NT - 2);

        // B fragments for the whole tile (4 n-frags x 2 ks = 8 reads)
        bf16x8 bfr[4][2];
#pragma unroll
        for (int n = 0; n < 4; ++n)
#pragma unroll
            for (int ks = 0; ks < 2; ++ks)
                bfr[n][ks] = __builtin_bit_cast(bf16x8,
                    *reinterpret_cast<const us8*>(&sBc[bSw[ks] + n * 16 * BK]));

#pragma unroll
        for (int m = 0; m < 4; ++m) {
            bf16x8 af[2];
#pragma unroll
            for (int ks = 0; ks < 2; ++ks)
                af[ks] = __builtin_bit_cast(bf16x8,
                    *reinterpret_cast<const us8*>(&sAc[aSw[ks] + m * 16 * BK]));
            // interleave next-next tile staging: m0:{0,4} m1:{1,5} m2:{2} m3:{3}
            if (doStage) {
                stage_unit(nb, kt + 2, m);
                if (m < 2) stage_unit(nb, kt + 2, 4 + m);
            }
            asm volatile("s_waitcnt lgkmcnt(0)" ::: "memory");
            __builtin_amdgcn_sched_barrier(0);   // rule #18: keep MFMA below wait
            __builtin_amdgcn_s_setprio(1);
#pragma unroll
            for (int n = 0; n < 4; ++n)
#pragma unroll
                for (int ks = 0; ks < 2; ++ks)
                    acc[m][n] = __builtin_amdgcn_mfma_f32_16x16x32_bf16(
                        af[ks], bfr[n][ks], acc[m][n], 0, 0, 0);
            __builtin_amdgcn_s_setprio(0);
        }
    }

    // epilogue: C/D layout col = lane&15, row = (lane>>4)*4 + r
    const int colBase = gy * BN + wc * 64 + (lane & 15);
    const int rowBase = gx * BM + wr * 64 + (lane >> 4) * 4;
#pragma unroll
    for (int n = 0; n < 4; ++n) {
        int col = colBase + n * 16;
        float bv = bias2[col];
#pragma unroll
        for (int m = 0; m < 4; ++m) {
            int row = rowBase + m * 16;
#pragma unroll
            for (int r = 0; r < 4; ++r)
                C[(size_t)(row + r) * OUT_DIM + col] = acc[m][n][r] + bv;
        }
    }
}

// ---- fallback (ws too small): fp32 LDS-staged, correct but slow ----
__global__ void taylor_naive(const float* __restrict__ x, const float* __restrict__ coeffs,
                             const float* __restrict__ bias, float* __restrict__ out) {
    int n = blockIdx.x;
    __shared__ float P[IN_DIM * 4];
    for (int i = threadIdx.x; i < IN_DIM; i += blockDim.x) {
        float xv = x[(size_t)n * IN_DIM + i];
        P[i * 4 + 0] = 1.f;
        P[i * 4 + 1] = xv;
        P[i * 4 + 2] = xv * xv;
        P[i * 4 + 3] = xv * xv * xv;
    }
    __syncthreads();
    for (int o = threadIdx.x; o < OUT_DIM; o += blockDim.x) {
        float s = bias[o];
        const float* c = coeffs + (size_t)o * (IN_DIM * 4);
        for (int i = 0; i < IN_DIM; ++i) {
            float4 cv = *reinterpret_cast<const float4*>(c + i * 4);
            s += cv.x * P[i * 4 + 0] + cv.y * P[i * 4 + 1] +
                 cv.z * P[i * 4 + 2] + cv.w * P[i * 4 + 3];
        }
        out[(size_t)n * OUT_DIM + o] = s;
    }
}

extern "C" void kernel_launch(void* const* d_in, const int* in_sizes, int n_in,
                              void* d_out, int out_size, void* d_ws, size_t ws_size,
                              hipStream_t stream) {
    const float* x = (const float*)d_in[0];
    const float* coeffs = (const float*)d_in[1];
    const float* bias = (const float*)d_in[2];
    float* out = (float*)d_out;

    const size_t needA = (size_t)NROWS * KD * 2;     // 48 MiB
    const size_t needB = (size_t)OUT_DIM * KD * 2;   // 6 MiB
    const size_t needBias = OUT_DIM * sizeof(float); // 4 KiB

    if (ws_size >= needA + needB + needBias) {
        unsigned short* A = (unsigned short*)d_ws;
        unsigned short* B = (unsigned short*)((char*)d_ws + needA);
        float* bias2 = (float*)((char*)d_ws + needA + needB);
        prep_coeffs<<<OUT_DIM, 256, 0, stream>>>(coeffs, bias, B, bias2);
        prep_powers<<<(NROWS * IN_DIM / 4) / 256, 256, 0, stream>>>(x, A);
        dim3 grid(NROWS / BM, OUT_DIM / BN);   // (32, 8) = 256 blocks, 1/CU
        taylor_gemm<<<grid, 512, 0, stream>>>(A, B, bias2, out);
    } else {
        taylor_naive<<<NROWS, 256, 0, stream>>>(x, coeffs, bias, out);
    }
}

// Round 5
// 87.912 us; speedup vs baseline: 1.3634x; 1.0245x over previous
//
#include <hip/hip_runtime.h>
#include <stdint.h>

#define IN_DIM 1024
#define OUT_DIM 1024
#define NROWS 8192
#define KD 3072            // k-major: K = (p-1)*1024 + i, p = 1..3 (k=0 folded into bias)

#define BM 256
#define BN 128
#define BK 64
#define NT (KD / BK)       // 48 K-tiles

typedef __bf16 bf16x8 __attribute__((ext_vector_type(8)));
typedef float f32x4 __attribute__((ext_vector_type(4)));
typedef unsigned short us8 __attribute__((ext_vector_type(8)));
typedef unsigned int u32;

#define AS1 __attribute__((address_space(1)))
#define AS3 __attribute__((address_space(3)))

__device__ __forceinline__ unsigned short f2bf(float f) {
    u32 u = __builtin_bit_cast(u32, f);
    u32 r = (u + 0x7fffu + ((u >> 16) & 1u)) >> 16;   // RNE, finite inputs
    return (unsigned short)r;
}

__device__ __forceinline__ bf16x8 ld8(const unsigned short* p) {
    return __builtin_bit_cast(bf16x8, *reinterpret_cast<const us8*>(p));
}

// ---- prep: coeffs fp32 -> bf16 B[OUT_DIM][KD] (k-major), c0 folded into bias2 ----
__global__ __launch_bounds__(256) void prep_coeffs(const float* __restrict__ c,
                                                   const float* __restrict__ bias,
                                                   unsigned short* __restrict__ B,
                                                   float* __restrict__ bias2) {
    const int o = blockIdx.x;
    const float4* row = reinterpret_cast<const float4*>(c + (size_t)o * (IN_DIM * 4));
    unsigned short* Bo = B + (size_t)o * KD;
    float s = 0.f;
    for (int i = threadIdx.x; i < IN_DIM; i += 256) {
        float4 v = row[i];            // {c0, c1, c2, c3} for (o, i)
        s += v.x;
        Bo[i]        = f2bf(v.y);
        Bo[1024 + i] = f2bf(v.z);
        Bo[2048 + i] = f2bf(v.w);
    }
#pragma unroll
    for (int off = 32; off; off >>= 1) s += __shfl_down(s, off);
    __shared__ float red[4];
    if ((threadIdx.x & 63) == 0) red[threadIdx.x >> 6] = s;
    __syncthreads();
    if (threadIdx.x == 0) bias2[o] = bias[o] + red[0] + red[1] + red[2] + red[3];
}

// ---- prep: powers of x -> bf16 A[NROWS][KD] (k-major) ----
__global__ __launch_bounds__(256) void prep_powers(const float* __restrict__ x,
                                                   unsigned short* __restrict__ A) {
    int t = blockIdx.x * blockDim.x + threadIdx.x;    // each handles 4 x values
    int n = t >> 8;                                   // 256 float4 per row
    int i4 = (t & 255) * 4;
    float4 v = reinterpret_cast<const float4*>(x)[t];
    unsigned short* An = A + (size_t)n * KD + i4;
    float xs[4] = {v.x, v.y, v.z, v.w};
    unsigned short b1[4], b2[4], b3[4];
#pragma unroll
    for (int j = 0; j < 4; ++j) {
        float x1 = xs[j], x2 = x1 * x1, x3 = x2 * x1;
        b1[j] = f2bf(x1); b2[j] = f2bf(x2); b3[j] = f2bf(x3);
    }
    ushort4 p1 = {b1[0], b1[1], b1[2], b1[3]};
    ushort4 p2 = {b2[0], b2[1], b2[2], b2[3]};
    ushort4 p3 = {b3[0], b3[1], b3[2], b3[3]};
    *reinterpret_cast<ushort4*>(An)        = p1;
    *reinterpret_cast<ushort4*>(An + 1024) = p2;
    *reinterpret_cast<ushort4*>(An + 2048) = p3;
}

// ---- main GEMM: C = A[M][KD] * B[N][KD]^T + bias2 ----
// 512 thr / 8 waves (4M x 2N, wave tile 64x64); BM=256 BN=128 BK=64.
// Register ping-pong pipeline: frags(kt) live in VGPRs while frags(kt+1)
// ds_reads are in flight under the MFMA cluster (T3); stage(kt+2) issued
// after barrier(kt) so it spans barrier(kt+1) (T4 counted-by-construction).
// T2 XOR-swizzle (rule #21), setprio (T5). Triple-buffered LDS, 1 block/CU.
__global__ __launch_bounds__(512, 2) void taylor_gemm(
    const unsigned short* __restrict__ A,   // bf16 [NROWS][KD]
    const unsigned short* __restrict__ B,   // bf16 [OUT_DIM][KD]
    const float* __restrict__ bias2,
    float* __restrict__ C) {
    __shared__ alignas(16) unsigned short sA[3][BM * BK];  // 3 x 32 KiB
    __shared__ alignas(16) unsigned short sB[3][BN * BK];  // 3 x 16 KiB

    const int tid = threadIdx.x;
    const int lane = tid & 63;
    const int wid = tid >> 6;       // 0..7
    const int wr = wid >> 1;        // 0..3  (M quarter: 64 rows)
    const int wc = wid & 1;         // 0..1  (N half: 64 cols)
    const int gx = blockIdx.x, gy = blockIdx.y;

    // ---- staging: 6 global_load_lds units/wave/tile (A:4, B:2) ----
    // LDS dest linear (base + lane*16); source col-slot XOR-permuted so a
    // swizzled read addr r*128B + (s^(r&7))*16B yields global slot s.
    const char* Ab = (const char*)A;
    const char* Bb = (const char*)B;
    const int cs = ((lane & 7) ^ (lane >> 3)) * 8;   // swizzled source col (ushort)
    size_t aSrc[4], bSrc[2];
    int aDst[4], bDst[2];
#pragma unroll
    for (int u = 0; u < 4; ++u) {
        int row = gx * BM + u * 64 + wid * 8 + (lane >> 3);
        aSrc[u] = ((size_t)row * KD + cs) * 2;
        aDst[u] = (u * 64 + wid * 8) * BK;
    }
#pragma unroll
    for (int u = 0; u < 2; ++u) {
        int row = gy * BN + u * 64 + wid * 8 + (lane >> 3);
        bSrc[u] = ((size_t)row * KD + cs) * 2;
        bDst[u] = (u * 64 + wid * 8) * BK;
    }

    auto stage_all = [&](int b, int kt) {
        size_t koff = (size_t)kt * (BK * 2);
#pragma unroll
        for (int u = 0; u < 4; ++u)
            __builtin_amdgcn_global_load_lds(
                (const AS1 void*)(Ab + aSrc[u] + koff),
                (AS3 void*)(&sA[b][aDst[u]]), 16, 0, 0);
#pragma unroll
        for (int u = 0; u < 2; ++u)
            __builtin_amdgcn_global_load_lds(
                (const AS1 void*)(Bb + bSrc[u] + koff),
                (AS3 void*)(&sB[b][bDst[u]]), 16, 0, 0);
    };

    // swizzled fragment read bases (ushort index), per ks:
    // row r = waveBase + frag*16 + (lane&15)  (r&7 == lane&7)
    // slot s = ks*4 + (lane>>4);  addr = r*64 + (s ^ (lane&7))*8
    int aSw[2], bSw[2];
#pragma unroll
    for (int ks = 0; ks < 2; ++ks) {
        int sw = ((ks * 4 + (lane >> 4)) ^ (lane & 7)) * 8;
        aSw[ks] = (wr * 64 + (lane & 15)) * BK + sw;
        bSw[ks] = (wc * 64 + (lane & 15)) * BK + sw;
    }

    bf16x8 fa0[4][2], fb0[4][2], fa1[4][2], fb1[4][2];
    f32x4 acc[4][4] = {};

    auto read_frags = [&](bf16x8 (&fa)[4][2], bf16x8 (&fb)[4][2], int b) {
        const unsigned short* sAc = &sA[b][0];
        const unsigned short* sBc = &sB[b][0];
#pragma unroll
        for (int n = 0; n < 4; ++n)
#pragma unroll
            for (int ks = 0; ks < 2; ++ks)
                fb[n][ks] = ld8(&sBc[bSw[ks] + n * 16 * BK]);
#pragma unroll
        for (int m = 0; m < 4; ++m)
#pragma unroll
            for (int ks = 0; ks < 2; ++ks)
                fa[m][ks] = ld8(&sAc[aSw[ks] + m * 16 * BK]);
    };

    auto mfma_all = [&](bf16x8 (&fa)[4][2], bf16x8 (&fb)[4][2]) {
        __builtin_amdgcn_s_setprio(1);
#pragma unroll
        for (int m = 0; m < 4; ++m)
#pragma unroll
            for (int n = 0; n < 4; ++n)
#pragma unroll
                for (int ks = 0; ks < 2; ++ks)
                    acc[m][n] = __builtin_amdgcn_mfma_f32_16x16x32_bf16(
                        fa[m][ks], fb[n][ks], acc[m][n], 0, 0, 0);
        __builtin_amdgcn_s_setprio(0);
    };

    // prologue: stage tiles 0,1; wait tile 0 only (tile 1 stays in flight);
    // preload frags(0) into set 0.
    stage_all(0, 0);
    stage_all(1, 1);
    asm volatile("s_waitcnt vmcnt(6)" ::: "memory");
    __builtin_amdgcn_s_barrier();
    __builtin_amdgcn_sched_barrier(0);
    read_frags(fa0, fb0, 0);

    // iter kt: vmcnt(0) = "stage(kt+1) landed" (only thing outstanding);
    // barrier; stage(kt+2); issue reads frags(kt+1); MFMA(kt) from regs.
    // Compiler inserts the counted lgkm wait before the NEXT iter's MFMA,
    // so ds_read latency hides under this iter's MFMA cluster.
#define TAYLOR_ITER(kt, FAc, FBc, FAn, FBn)                                   \
    {                                                                         \
        asm volatile("s_waitcnt vmcnt(0)" ::: "memory");                      \
        __builtin_amdgcn_s_barrier();                                         \
        __builtin_amdgcn_sched_barrier(0);                                    \
        if ((kt) < NT - 2) stage_all(((kt) + 2) % 3, (kt) + 2);               \
        if ((kt) < NT - 1) read_frags(FAn, FBn, ((kt) + 1) % 3);              \
        __builtin_amdgcn_sched_barrier(0);                                    \
        mfma_all(FAc, FBc);                                                   \
    }

    for (int kt = 0; kt < NT; kt += 2) {
        TAYLOR_ITER(kt,     fa0, fb0, fa1, fb1);
        TAYLOR_ITER(kt + 1, fa1, fb1, fa0, fb0);
    }
#undef TAYLOR_ITER

    // epilogue: C/D layout col = lane&15, row = (lane>>4)*4 + r
    const int colBase = gy * BN + wc * 64 + (lane & 15);
    const int rowBase = gx * BM + wr * 64 + (lane >> 4) * 4;
#pragma unroll
    for (int n = 0; n < 4; ++n) {
        int col = colBase + n * 16;
        float bv = bias2[col];
#pragma unroll
        for (int m = 0; m < 4; ++m) {
            int row = rowBase + m * 16;
#pragma unroll
            for (int r = 0; r < 4; ++r)
                C[(size_t)(row + r) * OUT_DIM + col] = acc[m][n][r] + bv;
        }
    }
}

// ---- fallback (ws too small): fp32 LDS-staged, correct but slow ----
__global__ void taylor_naive(const float* __restrict__ x, const float* __restrict__ coeffs,
                             const float* __restrict__ bias, float* __restrict__ out) {
    int n = blockIdx.x;
    __shared__ float P[IN_DIM * 4];
    for (int i = threadIdx.x; i < IN_DIM; i += blockDim.x) {
        float xv = x[(size_t)n * IN_DIM + i];
        P[i * 4 + 0] = 1.f;
        P[i * 4 + 1] = xv;
        P[i * 4 + 2] = xv * xv;
        P[i * 4 + 3] = xv * xv * xv;
    }
    __syncthreads();
    for (int o = threadIdx.x; o < OUT_DIM; o += blockDim.x) {
        float s = bias[o];
        const float* c = coeffs + (size_t)o * (IN_DIM * 4);
        for (int i = 0; i < IN_DIM; ++i) {
            float4 cv = *reinterpret_cast<const float4*>(c + i * 4);
            s += cv.x * P[i * 4 + 0] + cv.y * P[i * 4 + 1] +
                 cv.z * P[i * 4 + 2] + cv.w * P[i * 4 + 3];
        }
        out[(size_t)n * OUT_DIM + o] = s;
    }
}

extern "C" void kernel_launch(void* const* d_in, const int* in_sizes, int n_in,
                              void* d_out, int out_size, void* d_ws, size_t ws_size,
                              hipStream_t stream) {
    const float* x = (const float*)d_in[0];
    const float* coeffs = (const float*)d_in[1];
    const float* bias = (const float*)d_in[2];
    float* out = (float*)d_out;

    const size_t needA = (size_t)NROWS * KD * 2;     // 48 MiB
    const size_t needB = (size_t)OUT_DIM * KD * 2;   // 6 MiB
    const size_t needBias = OUT_DIM * sizeof(float); // 4 KiB

    if (ws_size >= needA + needB + needBias) {
        unsigned short* A = (unsigned short*)d_ws;
        unsigned short* B = (unsigned short*)((char*)d_ws + needA);
        float* bias2 = (float*)((char*)d_ws + needA + needB);
        prep_coeffs<<<OUT_DIM, 256, 0, stream>>>(coeffs, bias, B, bias2);
        prep_powers<<<(NROWS * IN_DIM / 4) / 256, 256, 0, stream>>>(x, A);
        dim3 grid(NROWS / BM, OUT_DIM / BN);   // (32, 8) = 256 blocks, 1/CU
        taylor_gemm<<<grid, 512, 0, stream>>>(A, B, bias2, out);
    } else {
        taylor_naive<<<NROWS, 256, 0, stream>>>(x, coeffs, bias, out);
    }
}